// Round 3
// baseline (3404.424 us; speedup 1.0000x reference)
//
#include <hip/hip_runtime.h>
#include <math.h>

#define D 1024
#define S 1024
#define NH 8
#define NKV 2
#define DH 128
#define NE 8
#define MLP 4096

using short8 = __attribute__((ext_vector_type(8))) short;
using f32x4 = __attribute__((ext_vector_type(4))) float;
typedef unsigned long long u64;
typedef unsigned short u16;

__device__ __forceinline__ u16 f2bf(float x) {
    unsigned u = __builtin_bit_cast(unsigned, x);
    return (u16)((u + 0x7fffu + ((u >> 16) & 1u)) >> 16);
}

// ---------------- fused resid-mix + rmsnorm; optional fp32 / bf16 outputs ----------------
__global__ void mix_rmsnorm_kernel(const float* __restrict__ x,
                                   const float* __restrict__ v1,
                                   const float* __restrict__ mix,
                                   float* __restrict__ xa,
                                   float* __restrict__ nrm,
                                   u16* __restrict__ nrmb) {
    int row = blockIdx.x, t = threadIdx.x;
    __shared__ float red[256];
    float vals[4];
    float ss = 0.f;
#pragma unroll
    for (int i = 0; i < 4; i++) {
        int d = t + i * 256;
        float xv = x[(size_t)row * D + d];
        if (v1) xv = mix[d] * xv + mix[D + d] * v1[(size_t)row * D + d];
        vals[i] = xv;
        ss += xv * xv;
    }
    red[t] = ss;
    __syncthreads();
    for (int s = 128; s > 0; s >>= 1) {
        if (t < s) red[t] += red[t + s];
        __syncthreads();
    }
    float r = rsqrtf(red[0] * (1.f / D) + 1e-6f);
#pragma unroll
    for (int i = 0; i < 4; i++) {
        int d = t + i * 256;
        float nv = vals[i] * r;
        if (xa) xa[(size_t)row * D + d] = vals[i];
        if (nrm) nrm[(size_t)row * D + d] = nv;
        if (nrmb) nrmb[(size_t)row * D + d] = f2bf(nv);
    }
}

// ---------------- generic bf16 MFMA GEMM: C[M,N] = A_bf16[M,K] @ bf16(B_fp32[K,N]) ----------------
// Tile 128x128, BK=32, 4 waves (2x2), each wave 64x64 = 4x4 mfma_f32_16x16x32_bf16 frags.
// mode 0: C fp32 = AB
// mode 1: C bf16 = silu(AB)
// mode 2: C fp32 = resid + scale[col] * AB
// mode 3: C fp32 [crowmap[row]] += rowwgt[row] * AB   (experts run sequentially -> race-free)
// mode 4: C bf16 = AB
// mode 5: C fp32 = causal(col<=row ? AB*rsqrt(128) : -1e9)
// transB: B is [N][K] row-major (used for Q.K^T). arowmap: A row gather. countPtr: device Meff.
// blockIdx.z batches heads via element strides abstride/bbstride/cbstride.
__launch_bounds__(256)
__global__ void mfma_gemm(const u16* __restrict__ A, int lda,
                          const float* __restrict__ B, int ldb,
                          void* __restrict__ Cv, int ldc,
                          int M, int N, int K, int mode, int transB,
                          size_t abstride, size_t bbstride, size_t cbstride,
                          const float* __restrict__ resid,
                          const float* __restrict__ scale,
                          const int* __restrict__ arowmap,
                          const int* __restrict__ crowmap,
                          const float* __restrict__ rowwgt,
                          const int* __restrict__ countPtr) {
    A += (size_t)blockIdx.z * abstride;
    B += (size_t)blockIdx.z * bbstride;
    size_t coff = (size_t)blockIdx.z * cbstride;
    float* Cf = (float*)Cv + coff;
    u16* Ch = (u16*)Cv + coff;

    int Meff = countPtr ? *countPtr : M;
    int m0 = blockIdx.y * 128, n0 = blockIdx.x * 128;
    int t = threadIdx.x;

    if (mode == 5 && n0 > m0 + 127) {  // fully-masked causal tile: fill and exit
#pragma unroll
        for (int i = 0; i < 64; i++) {
            int idx = t + i * 256;
            int r = idx >> 7, c = idx & 127;
            Cf[(size_t)(m0 + r) * ldc + n0 + c] = -1e9f;
        }
        return;
    }
    if (m0 >= Meff) return;

    __shared__ u16 As[128][36];
    __shared__ u16 Bs[128][36];
    int lane = t & 63, wid = t >> 6;
    int wr = wid >> 1, wc = wid & 1;
    int lg = lane >> 4, lr = lane & 15;

    f32x4 acc[4][4] = {};

    for (int k0 = 0; k0 < K; k0 += 32) {
        // stage A: 128 rows x 32 k (bf16 global, optional row gather)
#pragma unroll
        for (int i = 0; i < 4; i++) {
            int s = t + i * 256;           // 1024 u64 slots
            int r = s >> 3, kp = (s & 7) * 4;
            int gr = m0 + r;
            u64 v = 0;
            if (gr < Meff) {
                int ar = arowmap ? arowmap[gr] : gr;
                v = *(const u64*)&A[(size_t)ar * lda + k0 + kp];
            }
            *(u64*)&As[r][kp] = v;
        }
        // stage B -> Bs[n][k] (cast fp32->bf16 in flight)
        if (transB) {
#pragma unroll
            for (int i = 0; i < 4; i++) {
                int s = t + i * 256;
                int nr = s >> 3, kc = (s & 7) * 4;
                float4 bv = *(const float4*)&B[(size_t)(n0 + nr) * ldb + k0 + kc];
                u64 w = (u64)f2bf(bv.x) | ((u64)f2bf(bv.y) << 16) |
                        ((u64)f2bf(bv.z) << 32) | ((u64)f2bf(bv.w) << 48);
                *(u64*)&Bs[nr][kc] = w;
            }
        } else {
#pragma unroll
            for (int i = 0; i < 4; i++) {
                int s = t + i * 256;
                int nn = s & 127, q = s >> 7;  // q: 0..7 k-quads
                float b0 = B[(size_t)(k0 + q * 4 + 0) * ldb + n0 + nn];
                float b1 = B[(size_t)(k0 + q * 4 + 1) * ldb + n0 + nn];
                float b2 = B[(size_t)(k0 + q * 4 + 2) * ldb + n0 + nn];
                float b3 = B[(size_t)(k0 + q * 4 + 3) * ldb + n0 + nn];
                u64 w = (u64)f2bf(b0) | ((u64)f2bf(b1) << 16) |
                        ((u64)f2bf(b2) << 32) | ((u64)f2bf(b3) << 48);
                *(u64*)&Bs[nn][q * 4] = w;
            }
        }
        __syncthreads();

        short8 af[4], bfr[4];
        union U { u64 u[2]; short8 v; };
#pragma unroll
        for (int m = 0; m < 4; m++) {
            int row = wr * 64 + m * 16 + lr;
            U u;
            u.u[0] = *(const u64*)&As[row][lg * 4];
            u.u[1] = *(const u64*)&As[row][16 + lg * 4];
            af[m] = u.v;
        }
#pragma unroll
        for (int n = 0; n < 4; n++) {
            int row = wc * 64 + n * 16 + lr;
            U u;
            u.u[0] = *(const u64*)&Bs[row][lg * 4];
            u.u[1] = *(const u64*)&Bs[row][16 + lg * 4];
            bfr[n] = u.v;
        }
#pragma unroll
        for (int m = 0; m < 4; m++)
#pragma unroll
            for (int n = 0; n < 4; n++)
                acc[m][n] = __builtin_amdgcn_mfma_f32_16x16x32_bf16(af[m], bfr[n], acc[m][n], 0, 0, 0);
        __syncthreads();
    }

    // epilogue; C/D layout: col = lane&15, row = (lane>>4)*4 + reg  [verified m89/m91]
#pragma unroll
    for (int m = 0; m < 4; m++) {
#pragma unroll
        for (int n = 0; n < 4; n++) {
            int col = n0 + wc * 64 + n * 16 + lr;
#pragma unroll
            for (int i = 0; i < 4; i++) {
                int row = m0 + wr * 64 + m * 16 + lg * 4 + i;
                if (row >= Meff) continue;
                float v = acc[m][n][i];
                if (mode == 0) {
                    Cf[(size_t)row * ldc + col] = v;
                } else if (mode == 1) {
                    v = v / (1.f + expf(-v));
                    Ch[(size_t)row * ldc + col] = f2bf(v);
                } else if (mode == 2) {
                    Cf[(size_t)row * ldc + col] = resid[(size_t)row * ldc + col] + scale[col] * v;
                } else if (mode == 3) {
                    int tok = crowmap[row];
                    Cf[(size_t)tok * ldc + col] += rowwgt[row] * v;
                } else if (mode == 4) {
                    Ch[(size_t)row * ldc + col] = f2bf(v);
                } else {  // mode 5: causal scores
                    Cf[(size_t)row * ldc + col] = (col <= row) ? v * 0.08838834764831845f : -1e9f;
                }
            }
        }
    }
}

// ---------------- per-(token, head) QK rmsnorm * gain + RoPE ----------------
// q heads -> bf16 qbb; k heads -> fp32 kb in place (scores stages/casts it)
__global__ void qknorm_rope_kernel(float* __restrict__ q, float* __restrict__ k,
                                   u16* __restrict__ qbb,
                                   const float* __restrict__ gain) {
    int pos = blockIdx.x;
    int hh = blockIdx.y;  // 0..7 q heads, 8..9 k heads
    int lane = threadIdx.x;
    float* base = (hh < NH) ? q + (size_t)pos * (NH * DH) + hh * DH
                            : k + (size_t)pos * (NKV * DH) + (hh - NH) * DH;
    float x1 = base[lane], x2 = base[lane + 64];
    float ss = x1 * x1 + x2 * x2;
#pragma unroll
    for (int off = 32; off; off >>= 1) ss += __shfl_xor(ss, off);
    float r = rsqrtf(ss * (1.f / DH) + 1e-6f);
    float y1 = x1 * r * gain[lane];
    float y2 = x2 * r * gain[lane + 64];
    float inv = expf(-(float)lane * (1.f / 64.f) * 9.210340371976184f);
    float ang = (float)pos * inv;
    float sv, cv;
    sincosf(ang, &sv, &cv);
    float o1 = y1 * cv - y2 * sv;
    float o2 = y1 * sv + y2 * cv;
    if (hh < NH) {
        size_t o = (size_t)pos * (NH * DH) + hh * DH;
        qbb[o + lane] = f2bf(o1);
        qbb[o + lane + 64] = f2bf(o2);
    } else {
        base[lane] = o1;
        base[lane + 64] = o2;
    }
}

// ---------------- row softmax over S, in place; also emits bf16 P ----------------
__global__ void softmax_kernel(float* __restrict__ sc, u16* __restrict__ pb) {
    int h = blockIdx.y, qrow = blockIdx.x;
    size_t ro = ((size_t)h * S + qrow) * S;
    float* row = sc + ro;
    u16* prow = pb + ro;
    int t = threadIdx.x;
    __shared__ float red[256];
    float m = -3e38f;
    for (int i = t; i < S; i += 256) m = fmaxf(m, row[i]);
    red[t] = m;
    __syncthreads();
    for (int s = 128; s > 0; s >>= 1) {
        if (t < s) red[t] = fmaxf(red[t], red[t + s]);
        __syncthreads();
    }
    m = red[0];
    __syncthreads();
    float sum = 0.f;
    for (int i = t; i < S; i += 256) {
        float e = expf(row[i] - m);
        row[i] = e;
        sum += e;
    }
    red[t] = sum;
    __syncthreads();
    for (int s = 128; s > 0; s >>= 1) {
        if (t < s) red[t] += red[t + s];
        __syncthreads();
    }
    float inv = 1.f / red[0];
    for (int i = t; i < S; i += 256) prow[i] = f2bf(row[i] * inv);
}

// ---------------- zero moe accumulator + expert counters ----------------
__global__ void zero_kernel(float* __restrict__ moe, int* __restrict__ cnt) {
    size_t base = (size_t)blockIdx.x * 1024 + threadIdx.x * 4;
#pragma unroll
    for (int j = 0; j < 4; j++) moe[base + j] = 0.f;
    if (blockIdx.x == 0 && threadIdx.x < NE) cnt[threadIdx.x] = 0;
}

// ---------------- router: softmax over 8 logits, top-2, normalized, build lists ----------------
__global__ void router_kernel(const float* __restrict__ n2, const float* __restrict__ rw,
                              int* __restrict__ cnt, int* __restrict__ idxl,
                              float* __restrict__ wgtl) {
    int wid = threadIdx.x >> 6, lane = threadIdx.x & 63;
    int tkn = blockIdx.x * 4 + wid;
    if (tkn >= S) return;
    float acc[NE] = {};
    for (int i = 0; i < D / 64; i++) {
        int d = lane + i * 64;
        float xv = n2[(size_t)tkn * D + d];
#pragma unroll
        for (int e = 0; e < NE; e++) acc[e] += xv * rw[(size_t)d * NE + e];
    }
#pragma unroll
    for (int e = 0; e < NE; e++)
#pragma unroll
        for (int off = 32; off; off >>= 1) acc[e] += __shfl_down(acc[e], off);
    if (lane == 0) {
        float m = acc[0];
#pragma unroll
        for (int e = 1; e < NE; e++) m = fmaxf(m, acc[e]);
        float p[NE], sum = 0.f;
#pragma unroll
        for (int e = 0; e < NE; e++) {
            p[e] = expf(acc[e] - m);
            sum += p[e];
        }
#pragma unroll
        for (int e = 0; e < NE; e++) p[e] /= sum;
        int i1 = 0;
#pragma unroll
        for (int e = 1; e < NE; e++)
            if (p[e] > p[i1]) i1 = e;
        int i2 = -1;
#pragma unroll
        for (int e = 0; e < NE; e++) {
            if (e == i1) continue;
            if (i2 < 0 || p[e] > p[i2]) i2 = e;
        }
        float tot = p[i1] + p[i2];
        float w1v = p[i1] / tot, w2v = p[i2] / tot;
        int pos = atomicAdd(&cnt[i1], 1);
        idxl[i1 * S + pos] = tkn;
        wgtl[i1 * S + pos] = w1v;
        pos = atomicAdd(&cnt[i2], 1);
        idxl[i2 * S + pos] = tkn;
        wgtl[i2 * S + pos] = w2v;
    }
}

// ---------------- final: out = x2 + mlp_scale * moe ----------------
__global__ void final_kernel(const float* __restrict__ x2, const float* __restrict__ moe,
                             const float* __restrict__ mscale, float* __restrict__ out) {
    size_t base = (size_t)blockIdx.x * 1024 + threadIdx.x * 4;
#pragma unroll
    for (int j = 0; j < 4; j++) {
        size_t i = base + j;
        out[i] = x2[i] + mscale[i & (D - 1)] * moe[i];
    }
}

extern "C" void kernel_launch(void* const* d_in, const int* in_sizes, int n_in,
                              void* d_out, int out_size, void* d_ws, size_t ws_size,
                              hipStream_t stream) {
    const float* x = (const float*)d_in[0];
    const float* v1 = (const float*)d_in[1];
    const float* wq = (const float*)d_in[2];
    const float* wk = (const float*)d_in[3];
    const float* wv = (const float*)d_in[4];
    const float* wo = (const float*)d_in[5];
    const float* qk_gain = (const float*)d_in[6];
    const float* router_w = (const float*)d_in[7];
    const float* w1 = (const float*)d_in[8];
    const float* w2 = (const float*)d_in[9];
    const float* attn_scale = (const float*)d_in[10];
    const float* mlp_scale = (const float*)d_in[11];
    const float* resid_mix = (const float*)d_in[12];
    float* out = (float*)d_out;

    char* wsb = (char*)d_ws;
    const size_t MB = 1024 * 1024;
    float* xa = (float*)(wsb + 0 * MB);     // [S,D] fp32
    float* x2 = (float*)(wsb + 4 * MB);     // [S,D]
    float* n2 = (float*)(wsb + 8 * MB);     // [S,D]
    float* moe = (float*)(wsb + 12 * MB);   // [S,D]
    float* qb = (float*)(wsb + 16 * MB);    // [S,1024]
    float* kb = (float*)(wsb + 20 * MB);    // [S,256]
    float* vb = (float*)(wsb + 21 * MB);    // [S,256]
    u16* n1b = (u16*)(wsb + 22 * MB);       // [S,D] bf16
    u16* n2b = (u16*)(wsb + 24 * MB);       // [S,D]
    u16* obb = (u16*)(wsb + 26 * MB);       // [S,1024]
    u16* qbb = (u16*)(wsb + 28 * MB);       // [S,1024]
    u16* hidb = (u16*)(wsb + 32 * MB);      // [S,MLP]
    int* idxl = (int*)(wsb + 40 * MB);      // [8,S]
    float* wgtl = (float*)(wsb + 40 * MB + 32 * 1024);
    int* cnt = (int*)(wsb + 40 * MB + 64 * 1024);
    float* sc = (float*)(wsb + 44 * MB);    // [8,S,S] fp32
    u16* pb = (u16*)(wsb + 76 * MB);        // [8,S,S] bf16

    // x = mix0*x + mix1*v1 ; n1b = bf16(rmsnorm(x)) ; xa = mixed x
    mix_rmsnorm_kernel<<<S, 256, 0, stream>>>(x, v1, resid_mix, xa, nullptr, n1b);

    // q/k/v projections (fp32 out; rope consumes fp32)
    mfma_gemm<<<dim3(8, 8), 256, 0, stream>>>(n1b, D, wq, D, qb, D, S, D, D, 0, 0, 0, 0, 0,
                                              nullptr, nullptr, nullptr, nullptr, nullptr, nullptr);
    mfma_gemm<<<dim3(2, 8), 256, 0, stream>>>(n1b, D, wk, 256, kb, 256, S, 256, D, 0, 0, 0, 0, 0,
                                              nullptr, nullptr, nullptr, nullptr, nullptr, nullptr);
    mfma_gemm<<<dim3(2, 8), 256, 0, stream>>>(n1b, D, wv, 256, vb, 256, S, 256, D, 0, 0, 0, 0, 0,
                                              nullptr, nullptr, nullptr, nullptr, nullptr, nullptr);

    // qk-norm + gain + rope: q -> qbb (bf16), k -> kb (fp32, in place)
    qknorm_rope_kernel<<<dim3(S, NH + NKV), 64, 0, stream>>>(qb, kb, qbb, qk_gain);

    // scores: per head, A=qbb[:, h*128:...] bf16, B=kb rows (transB), causal epilogue
    // heads 0-3 share kv head 0; heads 4-7 share kv head 1
    mfma_gemm<<<dim3(8, 8, 4), 256, 0, stream>>>(qbb, D, kb, 256, sc, S, S, S, DH, 5, 1,
                                                 128, 0, (size_t)S * S,
                                                 nullptr, nullptr, nullptr, nullptr, nullptr, nullptr);
    mfma_gemm<<<dim3(8, 8, 4), 256, 0, stream>>>(qbb + 4 * DH, D, kb + DH, 256,
                                                 sc + 4 * (size_t)S * S, S, S, S, DH, 5, 1,
                                                 128, 0, (size_t)S * S,
                                                 nullptr, nullptr, nullptr, nullptr, nullptr, nullptr);
    // softmax (+ bf16 P)
    softmax_kernel<<<dim3(S, NH), 256, 0, stream>>>(sc, pb);

    // o = P @ V -> obb bf16 (per head; batched over 4 heads per kv group)
    mfma_gemm<<<dim3(1, 8, 4), 256, 0, stream>>>(pb, S, vb, 256, obb, D, S, DH, S, 4, 0,
                                                 (size_t)S * S, 0, DH,
                                                 nullptr, nullptr, nullptr, nullptr, nullptr, nullptr);
    mfma_gemm<<<dim3(1, 8, 4), 256, 0, stream>>>(pb + 4 * (size_t)S * S, S, vb + DH, 256,
                                                 obb + 4 * DH, D, S, DH, S, 4, 0,
                                                 (size_t)S * S, 0, DH,
                                                 nullptr, nullptr, nullptr, nullptr, nullptr, nullptr);

    // x2 = xa + attn_scale * (o @ wo)
    mfma_gemm<<<dim3(8, 8), 256, 0, stream>>>(obb, D, wo, D, x2, D, S, D, D, 2, 0, 0, 0, 0,
                                              xa, attn_scale, nullptr, nullptr, nullptr, nullptr);

    // n2 = rmsnorm(x2) (fp32 for router + bf16 for experts)
    mix_rmsnorm_kernel<<<S, 256, 0, stream>>>(x2, nullptr, nullptr, nullptr, n2, n2b);

    zero_kernel<<<1024, 256, 0, stream>>>(moe, cnt);
    router_kernel<<<S / 4, 256, 0, stream>>>(n2, router_w, cnt, idxl, wgtl);

    // experts: hidb = silu(gather(n2b) @ w1[e]) bf16 ; moe[tok] += w * (hidb @ w2[e])
    for (int e = 0; e < NE; e++) {
        mfma_gemm<<<dim3(32, 8), 256, 0, stream>>>(
            n2b, D, w1 + (size_t)e * D * MLP, MLP, hidb, MLP, S, MLP, D, 1, 0, 0, 0, 0,
            nullptr, nullptr, idxl + e * S, nullptr, nullptr, cnt + e);
        mfma_gemm<<<dim3(8, 8), 256, 0, stream>>>(
            hidb, MLP, w2 + (size_t)e * MLP * D, D, moe, D, S, D, MLP, 3, 0, 0, 0, 0,
            nullptr, nullptr, nullptr, idxl + e * S, wgtl + e * S, cnt + e);
    }

    // out = x2 + mlp_scale * moe
    final_kernel<<<1024, 256, 0, stream>>>(x2, moe, mlp_scale, out);
}